// Round 8
// baseline (365.491 us; speedup 1.0000x reference)
//
#include <hip/hip_runtime.h>
#include <stdint.h>

#define NPTS 1048576

using u16x8 = __attribute__((ext_vector_type(8))) unsigned short;
using f32x4 = __attribute__((ext_vector_type(4))) float;

// ---- FULL tier: x-duplicated (H, Wblk, [texA(32ch)|texB(32ch)]) bf16 layout
#define DUP_XY 0ul
#define DUP_XZ 16777216ul
#define DUP_YZ 33554432ul
#define DUP_XT 50331648ul
#define DUP_YT 50855936ul
#define DUP_ZT 51380224ul
#define WS_NEED_FULL 103809024ul

// ---- MID tier: plain (H,W,C) bf16 layout, 52 MB
#define PL_XY 0ul
#define PL_XZ 8388608ul
#define PL_YZ 16777216ul
#define PL_XT 25165824ul
#define PL_YT 25427968ul
#define PL_ZT 25690112ul
#define WS_NEED_MID  51904512ul

__device__ __forceinline__ float bf2f(unsigned short u) {
    union { unsigned int i; float f; } c; c.i = ((unsigned int)u) << 16; return c.f;
}
__device__ __forceinline__ unsigned int f2bf_bits(float f) {
    union { float f; unsigned int i; } c; c.f = f;
    unsigned int i = c.i;
    i += 0x7fffu + ((i >> 16) & 1u);   // round-to-nearest-even
    return i >> 16;
}

// ---------------------------------------------------------------------------
// FULL transpose (R7 verbatim): (C=32,H,W) fp32 -> x-duplicated bf16 blocks.
// ---------------------------------------------------------------------------
template<int WC, int W>
__global__ __launch_bounds__(256) void transpose_dup(const float* __restrict__ s0,
                                                     const float* __restrict__ s1,
                                                     const float* __restrict__ s2,
                                                     unsigned short* __restrict__ dst,
                                                     size_t planeStride) {
    __shared__ float tile[32][WC + 2];
    const float* src = (blockIdx.y == 0) ? s0 : (blockIdx.y == 1) ? s1 : s2;
    constexpr int CH = W / WC;
    const int h  = blockIdx.x / CH;
    const int w0 = (blockIdx.x % CH) * WC;
    const int HW = 512 * W;
    for (int i = threadIdx.x; i < 32 * (WC + 1); i += 256) {
        int c = i / (WC + 1), w = i - c * (WC + 1);
        int gw = min(w0 + w, W - 1);
        tile[c][w] = src[c * HW + h * W + gw];
    }
    __syncthreads();
    unsigned int* d = (unsigned int*)(dst + blockIdx.y * planeStride
                                          + (size_t)(h * W + w0) * 64);
    for (int idx = threadIdx.x; idx < WC * 32; idx += 256) {
        int blk = idx >> 5, j = idx & 31;
        int texsel = j >> 4, chp = j & 15;
        int col = blk + texsel;
        unsigned int lo = f2bf_bits(tile[chp * 2][col]);
        unsigned int hi = f2bf_bits(tile[chp * 2 + 1][col]);
        d[idx] = lo | (hi << 16);
    }
}

// ---------------------------------------------------------------------------
// FULL sampler, software-pipelined: all addresses first, loads issued
// 2-3 planes ahead of consumption.
// ---------------------------------------------------------------------------
struct PA {
    const unsigned short* b0;
    const unsigned short* b1;
    float w00, w01, w10, w11;
};

template<int W>
__device__ __forceinline__ PA mk_pa(const unsigned short* __restrict__ pl,
                                    float gw, float gh, int sub) {
    float ix = (gw + 1.0f) * 0.5f * (float)(W - 1);
    float iy = (gh + 1.0f) * 0.5f * 511.0f;
    float fx0 = fminf(fmaxf(floorf(ix), 0.0f), (float)(W - 1));
    float fy0 = fminf(fmaxf(floorf(iy), 0.0f), 511.0f);
    int ix0 = (int)fx0, iy0 = (int)fy0;
    int iy1 = min(iy0 + 1, 511);
    float wx = ix - fx0, wy = iy - fy0;
    PA a;
    a.b0 = pl + ((size_t)(iy0 * W + ix0) << 6) + sub * 8;
    a.b1 = pl + ((size_t)(iy1 * W + ix0) << 6) + sub * 8;
    float wx0 = 1.0f - wx, wy0 = 1.0f - wy;
    a.w00 = wx0 * wy0; a.w01 = wx * wy0; a.w10 = wx0 * wy; a.w11 = wx * wy;
    return a;
}

#define LOADP(n, A) \
    u16x8 v##n##0 = *(const u16x8*)((A).b0); \
    u16x8 v##n##1 = *(const u16x8*)((A).b0 + 32); \
    u16x8 v##n##2 = *(const u16x8*)((A).b1); \
    u16x8 v##n##3 = *(const u16x8*)((A).b1 + 32);

#define COMPP(n, A, OFF) { \
    f32x4 r0, r1; \
    _Pragma("unroll") \
    for (int j = 0; j < 4; ++j) \
        r0[j] = bf2f(v##n##0[j]) * (A).w00 + bf2f(v##n##1[j]) * (A).w01 \
              + bf2f(v##n##2[j]) * (A).w10 + bf2f(v##n##3[j]) * (A).w11; \
    _Pragma("unroll") \
    for (int j = 0; j < 4; ++j) \
        r1[j] = bf2f(v##n##0[4+j]) * (A).w00 + bf2f(v##n##1[4+j]) * (A).w01 \
              + bf2f(v##n##2[4+j]) * (A).w10 + bf2f(v##n##3[4+j]) * (A).w11; \
    __builtin_nontemporal_store(r0, (f32x4*)(o + (OFF))); \
    __builtin_nontemporal_store(r1, (f32x4*)(o + (OFF) + 4)); }

__global__ __launch_bounds__(256) void sample_dup_pipe(const float* __restrict__ x,
                                                       const unsigned short* __restrict__ ws,
                                                       float* __restrict__ out) {
    int tid = blockIdx.x * 256 + threadIdx.x;
    int p   = tid >> 2;
    int sub = tid & 3;
    f32x4 xv = *(const f32x4*)(x + (size_t)p * 4);
    float gx = (xv[0] * 0.5f + 0.5f) * 2.0f - 1.0f;
    float gy = (xv[1] * 0.5f + 0.5f) * 2.0f - 1.0f;
    float gz = (xv[2] * 0.5f + 0.5f) * 2.0f - 1.0f;
    float gt = (xv[3] * 0.5f + 0.5f) * 2.0f - 1.0f;
    float* o = out + (size_t)p * 192 + sub * 8;

    PA a0 = mk_pa<512>(ws + DUP_XY, gx, gy, sub);
    PA a1 = mk_pa<512>(ws + DUP_XZ, gx, gz, sub);
    PA a2 = mk_pa<512>(ws + DUP_YZ, gy, gz, sub);
    PA a3 = mk_pa<16 >(ws + DUP_XT, gx, gt, sub);
    PA a4 = mk_pa<16 >(ws + DUP_YT, gy, gt, sub);
    PA a5 = mk_pa<16 >(ws + DUP_ZT, gz, gt, sub);

    // pipeline: keep ~3 planes (12 loads) in flight ahead of each compute
    LOADP(0, a0)
    LOADP(1, a1)
    LOADP(2, a2)
    COMPP(0, a0, 0)
    LOADP(3, a3)
    COMPP(1, a1, 32)
    LOADP(4, a4)
    COMPP(2, a2, 64)
    LOADP(5, a5)
    COMPP(3, a3, 96)
    COMPP(4, a4, 128)
    COMPP(5, a5, 160)
}

// ---------------------------------------------------------------------------
// MID tier (proven): plain (H,W,C) transpose + unsorted sampler
// ---------------------------------------------------------------------------
template<int WC, int H, int W>
__global__ __launch_bounds__(256) void transpose3(const float* __restrict__ s0,
                                                  const float* __restrict__ s1,
                                                  const float* __restrict__ s2,
                                                  unsigned short* __restrict__ dst) {
    __shared__ float tile[32][WC + 1];
    const float* src = (blockIdx.y == 0) ? s0 : (blockIdx.y == 1) ? s1 : s2;
    constexpr int CH = W / WC;
    const int h  = blockIdx.x / CH;
    const int w0 = (blockIdx.x % CH) * WC;
    const int HW = H * W;
    const float* s = src + h * W + w0;
    for (int i = threadIdx.x; i < 32 * WC; i += 256) {
        int c = i / WC, w = i - c * WC;
        tile[c][w] = s[c * HW + w];
    }
    __syncthreads();
    unsigned int* d = (unsigned int*)(dst + (size_t)blockIdx.y * HW * 32
                                          + (size_t)(h * W + w0) * 32);
    for (int i = threadIdx.x; i < 16 * WC; i += 256) {
        int w = i >> 4, cp = i & 15;
        unsigned int lo = f2bf_bits(tile[cp * 2][w]);
        unsigned int hi = f2bf_bits(tile[cp * 2 + 1][w]);
        d[i] = lo | (hi << 16);
    }
}

template<int W, int H>
__device__ __forceinline__ void sample_one(const unsigned short* __restrict__ pl,
                                           float gw, float gh, int sub,
                                           float* __restrict__ o) {
    float ix = (gw + 1.0f) * 0.5f * (float)(W - 1);
    float iy = (gh + 1.0f) * 0.5f * (float)(H - 1);
    float fx0 = fminf(fmaxf(floorf(ix), 0.0f), (float)(W - 1));
    float fy0 = fminf(fmaxf(floorf(iy), 0.0f), (float)(H - 1));
    int ix0 = (int)fx0, iy0 = (int)fy0;
    int ix1 = min(ix0 + 1, W - 1), iy1 = min(iy0 + 1, H - 1);
    float wx = ix - fx0, wy = iy - fy0;
    float wx0 = 1.0f - wx, wy0 = 1.0f - wy;
    float w00 = wx0 * wy0, w01 = wx * wy0, w10 = wx0 * wy, w11 = wx * wy;
    const int base = sub * 8;
    u16x8 v00 = *(const u16x8*)(pl + ((iy0 * W + ix0) * 32 + base));
    u16x8 v01 = *(const u16x8*)(pl + ((iy0 * W + ix1) * 32 + base));
    u16x8 v10 = *(const u16x8*)(pl + ((iy1 * W + ix0) * 32 + base));
    u16x8 v11 = *(const u16x8*)(pl + ((iy1 * W + ix1) * 32 + base));
    f32x4 r0, r1;
#pragma unroll
    for (int j = 0; j < 4; ++j)
        r0[j] = bf2f(v00[j]) * w00 + bf2f(v01[j]) * w01
              + bf2f(v10[j]) * w10 + bf2f(v11[j]) * w11;
#pragma unroll
    for (int j = 0; j < 4; ++j)
        r1[j] = bf2f(v00[4 + j]) * w00 + bf2f(v01[4 + j]) * w01
              + bf2f(v10[4 + j]) * w10 + bf2f(v11[4 + j]) * w11;
    *(f32x4*)(o)     = r0;
    *(f32x4*)(o + 4) = r1;
}

__global__ __launch_bounds__(256) void sample_kernel(const float* __restrict__ x,
                                                     const unsigned short* __restrict__ ws,
                                                     float* __restrict__ out) {
    int tid = blockIdx.x * 256 + threadIdx.x;
    int p   = tid >> 2;
    int sub = tid & 3;
    f32x4 xv = *(const f32x4*)(x + (size_t)p * 4);
    float gx = (xv[0] * 0.5f + 0.5f) * 2.0f - 1.0f;
    float gy = (xv[1] * 0.5f + 0.5f) * 2.0f - 1.0f;
    float gz = (xv[2] * 0.5f + 0.5f) * 2.0f - 1.0f;
    float gt = (xv[3] * 0.5f + 0.5f) * 2.0f - 1.0f;
    float* o = out + (size_t)p * 192 + sub * 8;
    sample_one<512, 512>(ws + PL_XY, gx, gy, sub, o + 0);
    sample_one<512, 512>(ws + PL_XZ, gx, gz, sub, o + 32);
    sample_one<512, 512>(ws + PL_YZ, gy, gz, sub, o + 64);
    sample_one<16,  512>(ws + PL_XT, gx, gt, sub, o + 96);
    sample_one<16,  512>(ws + PL_YT, gy, gt, sub, o + 128);
    sample_one<16,  512>(ws + PL_ZT, gz, gt, sub, o + 160);
}

// last-resort direct fp32 fallback
template<int W, int H>
__device__ __forceinline__ void sample_direct_one(const float* __restrict__ pl,
                                                  float gw, float gh, int sub,
                                                  float* __restrict__ o) {
    float ix = (gw + 1.0f) * 0.5f * (float)(W - 1);
    float iy = (gh + 1.0f) * 0.5f * (float)(H - 1);
    float fx0 = fminf(fmaxf(floorf(ix), 0.0f), (float)(W - 1));
    float fy0 = fminf(fmaxf(floorf(iy), 0.0f), (float)(H - 1));
    int ix0 = (int)fx0, iy0 = (int)fy0;
    int ix1 = min(ix0 + 1, W - 1), iy1 = min(iy0 + 1, H - 1);
    float wx = ix - fx0, wy = iy - fy0;
    float wx0 = 1.0f - wx, wy0 = 1.0f - wy;
    float w00 = wx0 * wy0, w01 = wx * wy0, w10 = wx0 * wy, w11 = wx * wy;
    const int HW = W * H;
    int a00 = iy0 * W + ix0, a01 = iy0 * W + ix1;
    int a10 = iy1 * W + ix0, a11 = iy1 * W + ix1;
    const float* b = pl + (size_t)sub * 8 * HW;
#pragma unroll
    for (int j = 0; j < 8; ++j) {
        o[j] = b[a00] * w00 + b[a01] * w01 + b[a10] * w10 + b[a11] * w11;
        b += HW;
    }
}

__global__ __launch_bounds__(256) void sample_fallback(const float* __restrict__ x,
    const float* __restrict__ pxy, const float* __restrict__ pxz,
    const float* __restrict__ pyz, const float* __restrict__ pxt,
    const float* __restrict__ pyt, const float* __restrict__ pzt,
    float* __restrict__ out) {
    int tid = blockIdx.x * 256 + threadIdx.x;
    int p   = tid >> 2;
    int sub = tid & 3;
    f32x4 xv = *(const f32x4*)(x + (size_t)p * 4);
    float gx = (xv[0] * 0.5f + 0.5f) * 2.0f - 1.0f;
    float gy = (xv[1] * 0.5f + 0.5f) * 2.0f - 1.0f;
    float gz = (xv[2] * 0.5f + 0.5f) * 2.0f - 1.0f;
    float gt = (xv[3] * 0.5f + 0.5f) * 2.0f - 1.0f;
    float* o = out + (size_t)p * 192 + sub * 8;
    sample_direct_one<512, 512>(pxy, gx, gy, sub, o + 0);
    sample_direct_one<512, 512>(pxz, gx, gz, sub, o + 32);
    sample_direct_one<512, 512>(pyz, gy, gz, sub, o + 64);
    sample_direct_one<16,  512>(pxt, gx, gt, sub, o + 96);
    sample_direct_one<16,  512>(pyt, gy, gt, sub, o + 128);
    sample_direct_one<16,  512>(pzt, gz, gt, sub, o + 160);
}

extern "C" void kernel_launch(void* const* d_in, const int* in_sizes, int n_in,
                              void* d_out, int out_size, void* d_ws, size_t ws_size,
                              hipStream_t stream) {
    const float* x   = (const float*)d_in[0];
    const float* pxy = (const float*)d_in[1];
    const float* pxz = (const float*)d_in[2];
    const float* pyz = (const float*)d_in[3];
    const float* pxt = (const float*)d_in[4];
    const float* pyt = (const float*)d_in[5];
    const float* pzt = (const float*)d_in[6];
    float* out = (float*)d_out;

    if (ws_size >= WS_NEED_FULL) {
        unsigned short* ws = (unsigned short*)d_ws;
        transpose_dup<64, 512><<<dim3(512 * 8, 3), 256, 0, stream>>>(
            pxy, pxz, pyz, ws + DUP_XY, 16777216ul);
        transpose_dup<16, 16><<<dim3(512, 3), 256, 0, stream>>>(
            pxt, pyt, pzt, ws + DUP_XT, 524288ul);
        sample_dup_pipe<<<(NPTS * 4) / 256, 256, 0, stream>>>(x, ws, out);
    } else if (ws_size >= WS_NEED_MID) {
        unsigned short* planes = (unsigned short*)d_ws;
        transpose3<64, 512, 512><<<dim3(512 * 8, 3), 256, 0, stream>>>(pxy, pxz, pyz, planes);
        transpose3<16, 512, 16><<<dim3(512, 3), 256, 0, stream>>>(pxt, pyt, pzt, planes + PL_XT);
        sample_kernel<<<(NPTS * 4) / 256, 256, 0, stream>>>(x, planes, out);
    } else {
        sample_fallback<<<(NPTS * 4) / 256, 256, 0, stream>>>(x, pxy, pxz, pyz, pxt, pyt, pzt, out);
    }
}

// Round 9
// 350.836 us; speedup vs baseline: 1.0418x; 1.0418x over previous
//
#include <hip/hip_runtime.h>
#include <stdint.h>

#define NPTS 1048576

using u16x8 = __attribute__((ext_vector_type(8))) unsigned short;
using f32x4 = __attribute__((ext_vector_type(4))) float;

// ---- FULL tier: x-duplicated (H, Wblk, [texA(32ch)|texB(32ch)]) bf16 layout
// big planes: 512*512 blocks * 64 ch-entries = 16,777,216 elems (32 MiB) each
// t  planes:  512*16  blocks * 64            =    524,288 elems ( 1 MiB) each
#define DUP_XY 0ul
#define DUP_XZ 16777216ul
#define DUP_YZ 33554432ul
#define DUP_XT 50331648ul
#define DUP_YT 50855936ul
#define DUP_ZT 51380224ul
#define WS_NEED_FULL 103809024ul

// ---- MID tier: plain (H,W,C) bf16 layout (un-duplicated), 52 MB
#define PL_XY 0ul
#define PL_XZ 8388608ul
#define PL_YZ 16777216ul
#define PL_XT 25165824ul
#define PL_YT 25427968ul
#define PL_ZT 25690112ul
#define WS_NEED_MID  51904512ul

__device__ __forceinline__ float bf2f(unsigned short u) {
    union { unsigned int i; float f; } c; c.i = ((unsigned int)u) << 16; return c.f;
}
__device__ __forceinline__ unsigned int f2bf_bits(float f) {
    union { float f; unsigned int i; } c; c.f = f;
    unsigned int i = c.i;
    i += 0x7fffu + ((i >> 16) & 1u);   // round-to-nearest-even
    return i >> 16;
}

// ---------------------------------------------------------------------------
// FULL transpose: (C=32,H,W) fp32 -> x-duplicated bf16 blocks.
// Block dst[h][i] = [ texel(i) ch0..31 | texel(min(i+1,W-1)) ch0..31 ], 128B.
// ---------------------------------------------------------------------------
template<int WC, int W>
__global__ __launch_bounds__(256) void transpose_dup(const float* __restrict__ s0,
                                                     const float* __restrict__ s1,
                                                     const float* __restrict__ s2,
                                                     unsigned short* __restrict__ dst,
                                                     size_t planeStride) {
    __shared__ float tile[32][WC + 2];
    const float* src = (blockIdx.y == 0) ? s0 : (blockIdx.y == 1) ? s1 : s2;
    constexpr int CH = W / WC;
    const int h  = blockIdx.x / CH;
    const int w0 = (blockIdx.x % CH) * WC;
    const int HW = 512 * W;
    for (int i = threadIdx.x; i < 32 * (WC + 1); i += 256) {
        int c = i / (WC + 1), w = i - c * (WC + 1);
        int gw = min(w0 + w, W - 1);
        tile[c][w] = src[c * HW + h * W + gw];
    }
    __syncthreads();
    unsigned int* d = (unsigned int*)(dst + blockIdx.y * planeStride
                                          + (size_t)(h * W + w0) * 64);
    for (int idx = threadIdx.x; idx < WC * 32; idx += 256) {
        int blk = idx >> 5, j = idx & 31;       // 32 u32 words per 128B block
        int texsel = j >> 4, chp = j & 15;      // texA | texB ; channel pair
        int col = blk + texsel;
        unsigned int lo = f2bf_bits(tile[chp * 2][col]);
        unsigned int hi = f2bf_bits(tile[chp * 2 + 1][col]);
        d[idx] = lo | (hi << 16);               // coalesced
    }
}

// ---------------------------------------------------------------------------
// FULL sampler: bilinear from duplicated layout. Row-pair = ONE 128B line.
// 4 threads/point, 8 feats each; sequential 768B/pt output, NT stores.
// ---------------------------------------------------------------------------
template<int W>
__device__ __forceinline__ void sample_dup(const unsigned short* __restrict__ pl,
                                           float gw, float gh, int sub,
                                           float* __restrict__ o) {
    float ix = (gw + 1.0f) * 0.5f * (float)(W - 1);
    float iy = (gh + 1.0f) * 0.5f * 511.0f;
    float fx0 = fminf(fmaxf(floorf(ix), 0.0f), (float)(W - 1));
    float fy0 = fminf(fmaxf(floorf(iy), 0.0f), 511.0f);
    int ix0 = (int)fx0, iy0 = (int)fy0;
    int iy1 = min(iy0 + 1, 511);
    float wx = ix - fx0, wy = iy - fy0;
    float wx0 = 1.0f - wx, wy0 = 1.0f - wy;
    float w00 = wx0 * wy0, w01 = wx * wy0, w10 = wx0 * wy, w11 = wx * wy;
    const unsigned short* b0 = pl + ((size_t)(iy0 * W + ix0) << 6) + sub * 8;
    const unsigned short* b1 = pl + ((size_t)(iy1 * W + ix0) << 6) + sub * 8;
    u16x8 v00 = *(const u16x8*)(b0);            // texel ix0, row iy0
    u16x8 v01 = *(const u16x8*)(b0 + 32);       // texel ix1 (dup), same line
    u16x8 v10 = *(const u16x8*)(b1);
    u16x8 v11 = *(const u16x8*)(b1 + 32);
    f32x4 r0, r1;
#pragma unroll
    for (int j = 0; j < 4; ++j)
        r0[j] = bf2f(v00[j]) * w00 + bf2f(v01[j]) * w01
              + bf2f(v10[j]) * w10 + bf2f(v11[j]) * w11;
#pragma unroll
    for (int j = 0; j < 4; ++j)
        r1[j] = bf2f(v00[4 + j]) * w00 + bf2f(v01[4 + j]) * w01
              + bf2f(v10[4 + j]) * w10 + bf2f(v11[4 + j]) * w11;
    __builtin_nontemporal_store(r0, (f32x4*)(o));
    __builtin_nontemporal_store(r1, (f32x4*)(o + 4));
}

__global__ __launch_bounds__(256) void sample_dup_kernel(const float* __restrict__ x,
                                                         const unsigned short* __restrict__ ws,
                                                         float* __restrict__ out) {
    int tid = blockIdx.x * 256 + threadIdx.x;
    int p   = tid >> 2;
    int sub = tid & 3;
    f32x4 xv = *(const f32x4*)(x + (size_t)p * 4);
    float gx = (xv[0] * 0.5f + 0.5f) * 2.0f - 1.0f;
    float gy = (xv[1] * 0.5f + 0.5f) * 2.0f - 1.0f;
    float gz = (xv[2] * 0.5f + 0.5f) * 2.0f - 1.0f;
    float gt = (xv[3] * 0.5f + 0.5f) * 2.0f - 1.0f;
    float* o = out + (size_t)p * 192 + sub * 8;
    sample_dup<512>(ws + DUP_XY, gx, gy, sub, o + 0);
    sample_dup<512>(ws + DUP_XZ, gx, gz, sub, o + 32);
    sample_dup<512>(ws + DUP_YZ, gy, gz, sub, o + 64);
    sample_dup<16 >(ws + DUP_XT, gx, gt, sub, o + 96);
    sample_dup<16 >(ws + DUP_YT, gy, gt, sub, o + 128);
    sample_dup<16 >(ws + DUP_ZT, gz, gt, sub, o + 160);
}

// ---------------------------------------------------------------------------
// MID tier (proven round-1 path): plain (H,W,C) transpose + unsorted sampler
// ---------------------------------------------------------------------------
template<int WC, int H, int W>
__global__ __launch_bounds__(256) void transpose3(const float* __restrict__ s0,
                                                  const float* __restrict__ s1,
                                                  const float* __restrict__ s2,
                                                  unsigned short* __restrict__ dst) {
    __shared__ float tile[32][WC + 1];
    const float* src = (blockIdx.y == 0) ? s0 : (blockIdx.y == 1) ? s1 : s2;
    constexpr int CH = W / WC;
    const int h  = blockIdx.x / CH;
    const int w0 = (blockIdx.x % CH) * WC;
    const int HW = H * W;
    const float* s = src + h * W + w0;
    for (int i = threadIdx.x; i < 32 * WC; i += 256) {
        int c = i / WC, w = i - c * WC;
        tile[c][w] = s[c * HW + w];
    }
    __syncthreads();
    unsigned int* d = (unsigned int*)(dst + (size_t)blockIdx.y * HW * 32
                                          + (size_t)(h * W + w0) * 32);
    for (int i = threadIdx.x; i < 16 * WC; i += 256) {
        int w = i >> 4, cp = i & 15;
        unsigned int lo = f2bf_bits(tile[cp * 2][w]);
        unsigned int hi = f2bf_bits(tile[cp * 2 + 1][w]);
        d[i] = lo | (hi << 16);
    }
}

template<int W, int H>
__device__ __forceinline__ void sample_one(const unsigned short* __restrict__ pl,
                                           float gw, float gh, int sub,
                                           float* __restrict__ o) {
    float ix = (gw + 1.0f) * 0.5f * (float)(W - 1);
    float iy = (gh + 1.0f) * 0.5f * (float)(H - 1);
    float fx0 = fminf(fmaxf(floorf(ix), 0.0f), (float)(W - 1));
    float fy0 = fminf(fmaxf(floorf(iy), 0.0f), (float)(H - 1));
    int ix0 = (int)fx0, iy0 = (int)fy0;
    int ix1 = min(ix0 + 1, W - 1), iy1 = min(iy0 + 1, H - 1);
    float wx = ix - fx0, wy = iy - fy0;
    float wx0 = 1.0f - wx, wy0 = 1.0f - wy;
    float w00 = wx0 * wy0, w01 = wx * wy0, w10 = wx0 * wy, w11 = wx * wy;
    const int base = sub * 8;
    u16x8 v00 = *(const u16x8*)(pl + ((iy0 * W + ix0) * 32 + base));
    u16x8 v01 = *(const u16x8*)(pl + ((iy0 * W + ix1) * 32 + base));
    u16x8 v10 = *(const u16x8*)(pl + ((iy1 * W + ix0) * 32 + base));
    u16x8 v11 = *(const u16x8*)(pl + ((iy1 * W + ix1) * 32 + base));
    f32x4 r0, r1;
#pragma unroll
    for (int j = 0; j < 4; ++j)
        r0[j] = bf2f(v00[j]) * w00 + bf2f(v01[j]) * w01
              + bf2f(v10[j]) * w10 + bf2f(v11[j]) * w11;
#pragma unroll
    for (int j = 0; j < 4; ++j)
        r1[j] = bf2f(v00[4 + j]) * w00 + bf2f(v01[4 + j]) * w01
              + bf2f(v10[4 + j]) * w10 + bf2f(v11[4 + j]) * w11;
    *(f32x4*)(o)     = r0;
    *(f32x4*)(o + 4) = r1;
}

__global__ __launch_bounds__(256) void sample_kernel(const float* __restrict__ x,
                                                     const unsigned short* __restrict__ ws,
                                                     float* __restrict__ out) {
    int tid = blockIdx.x * 256 + threadIdx.x;
    int p   = tid >> 2;
    int sub = tid & 3;
    f32x4 xv = *(const f32x4*)(x + (size_t)p * 4);
    float gx = (xv[0] * 0.5f + 0.5f) * 2.0f - 1.0f;
    float gy = (xv[1] * 0.5f + 0.5f) * 2.0f - 1.0f;
    float gz = (xv[2] * 0.5f + 0.5f) * 2.0f - 1.0f;
    float gt = (xv[3] * 0.5f + 0.5f) * 2.0f - 1.0f;
    float* o = out + (size_t)p * 192 + sub * 8;
    sample_one<512, 512>(ws + PL_XY, gx, gy, sub, o + 0);
    sample_one<512, 512>(ws + PL_XZ, gx, gz, sub, o + 32);
    sample_one<512, 512>(ws + PL_YZ, gy, gz, sub, o + 64);
    sample_one<16,  512>(ws + PL_XT, gx, gt, sub, o + 96);
    sample_one<16,  512>(ws + PL_YT, gy, gt, sub, o + 128);
    sample_one<16,  512>(ws + PL_ZT, gz, gt, sub, o + 160);
}

// last-resort direct fp32 fallback
template<int W, int H>
__device__ __forceinline__ void sample_direct_one(const float* __restrict__ pl,
                                                  float gw, float gh, int sub,
                                                  float* __restrict__ o) {
    float ix = (gw + 1.0f) * 0.5f * (float)(W - 1);
    float iy = (gh + 1.0f) * 0.5f * (float)(H - 1);
    float fx0 = fminf(fmaxf(floorf(ix), 0.0f), (float)(W - 1));
    float fy0 = fminf(fmaxf(floorf(iy), 0.0f), (float)(H - 1));
    int ix0 = (int)fx0, iy0 = (int)fy0;
    int ix1 = min(ix0 + 1, W - 1), iy1 = min(iy0 + 1, H - 1);
    float wx = ix - fx0, wy = iy - fy0;
    float wx0 = 1.0f - wx, wy0 = 1.0f - wy;
    float w00 = wx0 * wy0, w01 = wx * wy0, w10 = wx0 * wy, w11 = wx * wy;
    const int HW = W * H;
    int a00 = iy0 * W + ix0, a01 = iy0 * W + ix1;
    int a10 = iy1 * W + ix0, a11 = iy1 * W + ix1;
    const float* b = pl + (size_t)sub * 8 * HW;
#pragma unroll
    for (int j = 0; j < 8; ++j) {
        o[j] = b[a00] * w00 + b[a01] * w01 + b[a10] * w10 + b[a11] * w11;
        b += HW;
    }
}

__global__ __launch_bounds__(256) void sample_fallback(const float* __restrict__ x,
    const float* __restrict__ pxy, const float* __restrict__ pxz,
    const float* __restrict__ pyz, const float* __restrict__ pxt,
    const float* __restrict__ pyt, const float* __restrict__ pzt,
    float* __restrict__ out) {
    int tid = blockIdx.x * 256 + threadIdx.x;
    int p   = tid >> 2;
    int sub = tid & 3;
    f32x4 xv = *(const f32x4*)(x + (size_t)p * 4);
    float gx = (xv[0] * 0.5f + 0.5f) * 2.0f - 1.0f;
    float gy = (xv[1] * 0.5f + 0.5f) * 2.0f - 1.0f;
    float gz = (xv[2] * 0.5f + 0.5f) * 2.0f - 1.0f;
    float gt = (xv[3] * 0.5f + 0.5f) * 2.0f - 1.0f;
    float* o = out + (size_t)p * 192 + sub * 8;
    sample_direct_one<512, 512>(pxy, gx, gy, sub, o + 0);
    sample_direct_one<512, 512>(pxz, gx, gz, sub, o + 32);
    sample_direct_one<512, 512>(pyz, gy, gz, sub, o + 64);
    sample_direct_one<16,  512>(pxt, gx, gt, sub, o + 96);
    sample_direct_one<16,  512>(pyt, gy, gt, sub, o + 128);
    sample_direct_one<16,  512>(pzt, gz, gt, sub, o + 160);
}

extern "C" void kernel_launch(void* const* d_in, const int* in_sizes, int n_in,
                              void* d_out, int out_size, void* d_ws, size_t ws_size,
                              hipStream_t stream) {
    const float* x   = (const float*)d_in[0];
    const float* pxy = (const float*)d_in[1];
    const float* pxz = (const float*)d_in[2];
    const float* pyz = (const float*)d_in[3];
    const float* pxt = (const float*)d_in[4];
    const float* pyt = (const float*)d_in[5];
    const float* pzt = (const float*)d_in[6];
    float* out = (float*)d_out;

    if (ws_size >= WS_NEED_FULL) {
        unsigned short* ws = (unsigned short*)d_ws;
        // big planes -> duplicated blocks (32 MiB each)
        transpose_dup<64, 512><<<dim3(512 * 8, 3), 256, 0, stream>>>(
            pxy, pxz, pyz, ws + DUP_XY, 16777216ul);
        // t planes -> duplicated blocks (1 MiB each)
        transpose_dup<16, 16><<<dim3(512, 3), 256, 0, stream>>>(
            pxt, pyt, pzt, ws + DUP_XT, 524288ul);
        sample_dup_kernel<<<(NPTS * 4) / 256, 256, 0, stream>>>(x, ws, out);
    } else if (ws_size >= WS_NEED_MID) {
        unsigned short* planes = (unsigned short*)d_ws;
        transpose3<64, 512, 512><<<dim3(512 * 8, 3), 256, 0, stream>>>(pxy, pxz, pyz, planes);
        transpose3<16, 512, 16><<<dim3(512, 3), 256, 0, stream>>>(pxt, pyt, pzt, planes + PL_XT);
        sample_kernel<<<(NPTS * 4) / 256, 256, 0, stream>>>(x, planes, out);
    } else {
        sample_fallback<<<(NPTS * 4) / 256, 256, 0, stream>>>(x, pxy, pxz, pyz, pxt, pyt, pzt, out);
    }
}